// Round 1
// baseline (1439.911 us; speedup 1.0000x reference)
//
#include <hip/hip_runtime.h>
#include <math.h>

#define NN 10000
#define NE 160000
#define CH 128
#define SCALE_F 0.0625f
#define EPS_F 1.1920929e-07f

// ---------------------------------------------------------------------------
// Kernel 0: initialize out = [s | v]  (out is poisoned 0xAA before every call)
// ---------------------------------------------------------------------------
__global__ __launch_bounds__(256) void init_out_kernel(const float4* __restrict__ s,
                                                       const float4* __restrict__ v,
                                                       float4* __restrict__ out) {
    int idx = blockIdx.x * 256 + threadIdx.x;   // 0 .. 1,279,999
    const int ns4 = NN * CH / 4;                // 320,000 float4 of s
    out[idx] = (idx < ns4) ? s[idx] : v[idx - ns4];
}

// ---------------------------------------------------------------------------
// Kernel 0b: detect whether edge_index is stored as int64 (all odd int32
// words == 0, since indices < 2^31) or int32. Writes flag to ws.
// ---------------------------------------------------------------------------
__global__ void detect_i64_kernel(const int* __restrict__ ei, int* __restrict__ flag) {
    int t = threadIdx.x;                 // 64 threads
    int val = ei[2 * t + 1];             // high words if int64; random indices if int32
    unsigned long long b = __ballot(val != 0);
    if (t == 0) *flag = (b == 0ULL) ? 1 : 0;
}

// ---------------------------------------------------------------------------
// Kernel 1: phi = (b2 + w2 @ silu(b1 + w1 @ rmsnorm(s)))   [NN x 384]
// 8 nodes per block, 256 threads.
// ---------------------------------------------------------------------------
__global__ __launch_bounds__(256) void phi_kernel(const float* __restrict__ s,
                                                  const float* __restrict__ w1,
                                                  const float* __restrict__ b1,
                                                  const float* __restrict__ w2,
                                                  const float* __restrict__ b2,
                                                  const float* __restrict__ rms_w,
                                                  float* __restrict__ phi) {
    __shared__ float sn[8][132];   // padded rows (132*4 B = 16B-aligned, odd float4 stride)
    __shared__ float hh[8][132];

    const int t = threadIdx.x;
    const int n0 = blockIdx.x * 8;

    // --- RMSNorm: thread t handles node m = t>>5, 4 channels at l*4 ---
    {
        const int m = t >> 5;
        const int l = t & 31;
        const int n = n0 + m;
        float4 sv = ((const float4*)(s + (size_t)n * CH))[l];
        float ss = sv.x * sv.x + sv.y * sv.y + sv.z * sv.z + sv.w * sv.w;
        #pragma unroll
        for (int off = 16; off > 0; off >>= 1) ss += __shfl_xor(ss, off, 32);
        const float sc = rsqrtf(ss * (1.0f / CH) + EPS_F);
        float4 rw = ((const float4*)rms_w)[l];
        float4* dst = (float4*)&sn[m][l * 4];
        float4 o;
        o.x = sv.x * sc * rw.x;
        o.y = sv.y * sc * rw.y;
        o.z = sv.z * sc * rw.z;
        o.w = sv.w * sc * rw.w;
        *dst = o;
    }
    __syncthreads();

    const int d  = t & 127;          // output channel
    const int mh = (t >> 7) * 4;     // node sub-group: 0 or 4

    // --- Phase 1: h = silu(s_norm @ w1^T + b1) ---
    {
        float acc0, acc1, acc2, acc3;
        const float bb = b1[d];
        acc0 = acc1 = acc2 = acc3 = bb;
        const float4* w1v = (const float4*)(w1 + (size_t)d * CH);
        #pragma unroll 4
        for (int kc = 0; kc < 32; ++kc) {
            float4 w = w1v[kc];
            float4 s0 = *(const float4*)&sn[mh + 0][kc * 4];
            float4 s1 = *(const float4*)&sn[mh + 1][kc * 4];
            float4 s2 = *(const float4*)&sn[mh + 2][kc * 4];
            float4 s3 = *(const float4*)&sn[mh + 3][kc * 4];
            acc0 += w.x * s0.x + w.y * s0.y + w.z * s0.z + w.w * s0.w;
            acc1 += w.x * s1.x + w.y * s1.y + w.z * s1.z + w.w * s1.w;
            acc2 += w.x * s2.x + w.y * s2.y + w.z * s2.z + w.w * s2.w;
            acc3 += w.x * s3.x + w.y * s3.y + w.z * s3.z + w.w * s3.w;
        }
        hh[mh + 0][d] = acc0 / (1.0f + __expf(-acc0));
        hh[mh + 1][d] = acc1 / (1.0f + __expf(-acc1));
        hh[mh + 2][d] = acc2 / (1.0f + __expf(-acc2));
        hh[mh + 3][d] = acc3 / (1.0f + __expf(-acc3));
    }
    __syncthreads();

    // --- Phase 2: phi = h @ w2^T + b2 (3 output rows per thread: d, 128+d, 256+d) ---
    {
        float a[3][4];
        #pragma unroll
        for (int q = 0; q < 3; ++q) {
            float bb = b2[q * 128 + d];
            a[q][0] = a[q][1] = a[q][2] = a[q][3] = bb;
        }
        const float4* w2v0 = (const float4*)(w2 + (size_t)(0 * 128 + d) * CH);
        const float4* w2v1 = (const float4*)(w2 + (size_t)(1 * 128 + d) * CH);
        const float4* w2v2 = (const float4*)(w2 + (size_t)(2 * 128 + d) * CH);
        #pragma unroll 2
        for (int kc = 0; kc < 32; ++kc) {
            float4 h0 = *(const float4*)&hh[mh + 0][kc * 4];
            float4 h1 = *(const float4*)&hh[mh + 1][kc * 4];
            float4 h2 = *(const float4*)&hh[mh + 2][kc * 4];
            float4 h3 = *(const float4*)&hh[mh + 3][kc * 4];
            float4 w0 = w2v0[kc];
            float4 w1r = w2v1[kc];
            float4 w2r = w2v2[kc];
            a[0][0] += w0.x * h0.x + w0.y * h0.y + w0.z * h0.z + w0.w * h0.w;
            a[0][1] += w0.x * h1.x + w0.y * h1.y + w0.z * h1.z + w0.w * h1.w;
            a[0][2] += w0.x * h2.x + w0.y * h2.y + w0.z * h2.z + w0.w * h2.w;
            a[0][3] += w0.x * h3.x + w0.y * h3.y + w0.z * h3.z + w0.w * h3.w;
            a[1][0] += w1r.x * h0.x + w1r.y * h0.y + w1r.z * h0.z + w1r.w * h0.w;
            a[1][1] += w1r.x * h1.x + w1r.y * h1.y + w1r.z * h1.z + w1r.w * h1.w;
            a[1][2] += w1r.x * h2.x + w1r.y * h2.y + w1r.z * h2.z + w1r.w * h2.w;
            a[1][3] += w1r.x * h3.x + w1r.y * h3.y + w1r.z * h3.z + w1r.w * h3.w;
            a[2][0] += w2r.x * h0.x + w2r.y * h0.y + w2r.z * h0.z + w2r.w * h0.w;
            a[2][1] += w2r.x * h1.x + w2r.y * h1.y + w2r.z * h1.z + w2r.w * h1.w;
            a[2][2] += w2r.x * h2.x + w2r.y * h2.y + w2r.z * h2.z + w2r.w * h2.w;
            a[2][3] += w2r.x * h3.x + w2r.y * h3.y + w2r.z * h3.z + w2r.w * h3.w;
        }
        #pragma unroll
        for (int mm = 0; mm < 4; ++mm) {
            float* p = phi + (size_t)(n0 + mh + mm) * 384;
            p[0 * 128 + d] = a[0][mm];
            p[1 * 128 + d] = a[1][mm];
            p[2 * 128 + d] = a[2][mm];
        }
    }
}

// ---------------------------------------------------------------------------
// Kernel 2: edge scatter. 32 lanes per edge (4 channels each), 8 edges/block.
// ---------------------------------------------------------------------------
__global__ __launch_bounds__(256) void edge_kernel(const int* __restrict__ ei,
                                                   const int* __restrict__ i64flag,
                                                   const float* __restrict__ phi,
                                                   const float* __restrict__ rbf,
                                                   const float* __restrict__ v,
                                                   const float* __restrict__ ev,
                                                   float* __restrict__ out_s,
                                                   float* __restrict__ out_v) {
    const int t = threadIdx.x;
    const int e = blockIdx.x * 8 + (t >> 5);
    if (e >= NE) return;
    const int l = t & 31;

    const int is64 = *i64flag;
    int i, j;
    if (is64) {
        i = ei[2 * (size_t)e];
        j = ei[2 * ((size_t)NE + e)];
    } else {
        i = ei[e];
        j = ei[NE + e];
    }

    const float4* pj = (const float4*)(phi + (size_t)j * 384);
    const float4* rb = (const float4*)(rbf + (size_t)e * 384);

    float4 ps  = pj[l],      rs  = rb[l];
    float4 pvv = pj[32 + l], rvv = rb[32 + l];
    float4 pvs = pj[64 + l], rvs = rb[64 + l];

    float4 ms, mvv, mvs;
    ms.x = ps.x * rs.x;   ms.y = ps.y * rs.y;   ms.z = ps.z * rs.z;   ms.w = ps.w * rs.w;
    mvv.x = pvv.x * rvv.x; mvv.y = pvv.y * rvv.y; mvv.z = pvv.z * rvv.z; mvv.w = pvv.w * rvv.w;
    mvs.x = pvs.x * rvs.x; mvs.y = pvs.y * rvs.y; mvs.z = pvs.z * rvs.z; mvs.w = pvs.w * rvs.w;

    const float e0 = ev[(size_t)e * 3 + 0];
    const float e1 = ev[(size_t)e * 3 + 1];
    const float e2 = ev[(size_t)e * 3 + 2];

    const int c = l * 4;
    float* os = out_s + (size_t)i * CH + c;
    atomicAdd(os + 0, SCALE_F * ms.x);
    atomicAdd(os + 1, SCALE_F * ms.y);
    atomicAdd(os + 2, SCALE_F * ms.z);
    atomicAdd(os + 3, SCALE_F * ms.w);

    const float evd[3] = {e0, e1, e2};
    #pragma unroll
    for (int dd = 0; dd < 3; ++dd) {
        float4 vv = ((const float4*)(v + ((size_t)j * 3 + dd) * CH))[l];
        float4 g;
        g.x = vv.x * mvv.x + evd[dd] * mvs.x;
        g.y = vv.y * mvv.y + evd[dd] * mvs.y;
        g.z = vv.z * mvv.z + evd[dd] * mvs.z;
        g.w = vv.w * mvv.w + evd[dd] * mvs.w;
        float* ov = out_v + ((size_t)i * 3 + dd) * CH + c;
        atomicAdd(ov + 0, SCALE_F * g.x);
        atomicAdd(ov + 1, SCALE_F * g.y);
        atomicAdd(ov + 2, SCALE_F * g.z);
        atomicAdd(ov + 3, SCALE_F * g.w);
    }
}

// ---------------------------------------------------------------------------
extern "C" void kernel_launch(void* const* d_in, const int* in_sizes, int n_in,
                              void* d_out, int out_size, void* d_ws, size_t ws_size,
                              hipStream_t stream) {
    const float* s    = (const float*)d_in[0];
    const float* v    = (const float*)d_in[1];
    const int*   ei   = (const int*)d_in[2];
    const float* rbf  = (const float*)d_in[3];
    const float* ev   = (const float*)d_in[4];
    const float* w1   = (const float*)d_in[5];
    const float* b1   = (const float*)d_in[6];
    const float* w2   = (const float*)d_in[7];
    const float* b2   = (const float*)d_in[8];
    const float* rmsw = (const float*)d_in[9];

    float* out   = (float*)d_out;
    float* out_s = out;                       // [NN,1,CH]
    float* out_v = out + (size_t)NN * CH;     // [NN,3,CH]

    float* phi = (float*)d_ws;                             // NN*384 floats = 15.36 MB
    int* i64flag = (int*)((char*)d_ws + (size_t)NN * 384 * sizeof(float));

    init_out_kernel<<<(NN * 4 * CH / 4) / 256, 256, 0, stream>>>(
        (const float4*)s, (const float4*)v, (float4*)out);
    detect_i64_kernel<<<1, 64, 0, stream>>>(ei, i64flag);
    phi_kernel<<<NN / 8, 256, 0, stream>>>(s, w1, b1, w2, b2, rmsw, phi);
    edge_kernel<<<NE / 8, 256, 0, stream>>>(ei, i64flag, phi, rbf, v, ev, out_s, out_v);
}

// Round 2
// 524.846 us; speedup vs baseline: 2.7435x; 2.7435x over previous
//
#include <hip/hip_runtime.h>
#include <math.h>

#define NN 10000
#define NE 160000
#define CH 128
#define SCALE_F 0.0625f
#define EPS_F 1.1920929e-07f

// ---------------------------------------------------------------------------
// Kernel: detect whether edge_index is stored as int64 (all odd int32
// words == 0, since indices < 2^31) or int32. Writes flag to ws.
// ---------------------------------------------------------------------------
__global__ void detect_i64_kernel(const int* __restrict__ ei, int* __restrict__ flag) {
    int t = threadIdx.x;                 // 64 threads
    int val = ei[2 * t + 1];             // high words if int64; random indices if int32
    unsigned long long b = __ballot(val != 0);
    if (t == 0) *flag = (b == 0ULL) ? 1 : 0;
}

// ---------------------------------------------------------------------------
// CSR construction: zero counts -> count -> scan -> bucket
// ---------------------------------------------------------------------------
__global__ __launch_bounds__(256) void zero_counts_kernel(int* __restrict__ counts) {
    int t = blockIdx.x * 256 + threadIdx.x;
    if (t < NN) counts[t] = 0;
}

__global__ __launch_bounds__(256) void count_kernel(const int* __restrict__ ei,
                                                    const int* __restrict__ flag,
                                                    int* __restrict__ counts) {
    int e = blockIdx.x * 256 + threadIdx.x;
    if (e >= NE) return;
    int i = (*flag) ? ei[2 * (size_t)e] : ei[e];
    atomicAdd(&counts[i], 1);
}

// Single-block exclusive scan over NN counts -> offsets (and cursor copy).
__global__ __launch_bounds__(1024) void scan_kernel(const int* __restrict__ counts,
                                                    int* __restrict__ offsets,
                                                    int* __restrict__ cursor) {
    __shared__ int sm[1024];
    const int t = threadIdx.x;
    const int base = t * 10;                 // 1024*10 = 10240 >= NN
    int vals[10];
    int lsum = 0;
    #pragma unroll
    for (int k = 0; k < 10; ++k) {
        int idx = base + k;
        int v = (idx < NN) ? counts[idx] : 0;
        vals[k] = v;
        lsum += v;
    }
    sm[t] = lsum;
    __syncthreads();
    #pragma unroll
    for (int off = 1; off < 1024; off <<= 1) {
        int add = (t >= off) ? sm[t - off] : 0;
        __syncthreads();
        sm[t] += add;
        __syncthreads();
    }
    int run = sm[t] - lsum;                  // exclusive prefix of this thread's chunk
    #pragma unroll
    for (int k = 0; k < 10; ++k) {
        int idx = base + k;
        if (idx < NN) { offsets[idx] = run; cursor[idx] = run; }
        run += vals[k];
    }
}

__global__ __launch_bounds__(256) void bucket_kernel(const int* __restrict__ ei,
                                                     const int* __restrict__ flag,
                                                     int* __restrict__ cursor,
                                                     int2* __restrict__ bucket) {
    int e = blockIdx.x * 256 + threadIdx.x;
    if (e >= NE) return;
    int i, j;
    if (*flag) {
        i = ei[2 * (size_t)e];
        j = ei[2 * ((size_t)NE + e)];
    } else {
        i = ei[e];
        j = ei[NE + e];
    }
    int pos = atomicAdd(&cursor[i], 1);
    bucket[pos] = make_int2(e, j);
}

// ---------------------------------------------------------------------------
// Kernel: phi = (b2 + w2 @ silu(b1 + w1 @ rmsnorm(s)))   [NN x 384]
// 8 nodes per block, 256 threads.
// ---------------------------------------------------------------------------
__global__ __launch_bounds__(256) void phi_kernel(const float* __restrict__ s,
                                                  const float* __restrict__ w1,
                                                  const float* __restrict__ b1,
                                                  const float* __restrict__ w2,
                                                  const float* __restrict__ b2,
                                                  const float* __restrict__ rms_w,
                                                  float* __restrict__ phi) {
    __shared__ float sn[8][132];
    __shared__ float hh[8][132];

    const int t = threadIdx.x;
    const int n0 = blockIdx.x * 8;

    // --- RMSNorm: thread t handles node m = t>>5, 4 channels at l*4 ---
    {
        const int m = t >> 5;
        const int l = t & 31;
        const int n = n0 + m;
        float4 sv = ((const float4*)(s + (size_t)n * CH))[l];
        float ss = sv.x * sv.x + sv.y * sv.y + sv.z * sv.z + sv.w * sv.w;
        #pragma unroll
        for (int off = 16; off > 0; off >>= 1) ss += __shfl_xor(ss, off, 32);
        const float sc = rsqrtf(ss * (1.0f / CH) + EPS_F);
        float4 rw = ((const float4*)rms_w)[l];
        float4* dst = (float4*)&sn[m][l * 4];
        float4 o;
        o.x = sv.x * sc * rw.x;
        o.y = sv.y * sc * rw.y;
        o.z = sv.z * sc * rw.z;
        o.w = sv.w * sc * rw.w;
        *dst = o;
    }
    __syncthreads();

    const int d  = t & 127;          // output channel
    const int mh = (t >> 7) * 4;     // node sub-group: 0 or 4

    // --- Phase 1: h = silu(s_norm @ w1^T + b1) ---
    {
        float acc0, acc1, acc2, acc3;
        const float bb = b1[d];
        acc0 = acc1 = acc2 = acc3 = bb;
        const float4* w1v = (const float4*)(w1 + (size_t)d * CH);
        #pragma unroll 4
        for (int kc = 0; kc < 32; ++kc) {
            float4 w = w1v[kc];
            float4 s0 = *(const float4*)&sn[mh + 0][kc * 4];
            float4 s1 = *(const float4*)&sn[mh + 1][kc * 4];
            float4 s2 = *(const float4*)&sn[mh + 2][kc * 4];
            float4 s3 = *(const float4*)&sn[mh + 3][kc * 4];
            acc0 += w.x * s0.x + w.y * s0.y + w.z * s0.z + w.w * s0.w;
            acc1 += w.x * s1.x + w.y * s1.y + w.z * s1.z + w.w * s1.w;
            acc2 += w.x * s2.x + w.y * s2.y + w.z * s2.z + w.w * s2.w;
            acc3 += w.x * s3.x + w.y * s3.y + w.z * s3.z + w.w * s3.w;
        }
        hh[mh + 0][d] = acc0 / (1.0f + __expf(-acc0));
        hh[mh + 1][d] = acc1 / (1.0f + __expf(-acc1));
        hh[mh + 2][d] = acc2 / (1.0f + __expf(-acc2));
        hh[mh + 3][d] = acc3 / (1.0f + __expf(-acc3));
    }
    __syncthreads();

    // --- Phase 2: phi = h @ w2^T + b2 ---
    {
        float a[3][4];
        #pragma unroll
        for (int q = 0; q < 3; ++q) {
            float bb = b2[q * 128 + d];
            a[q][0] = a[q][1] = a[q][2] = a[q][3] = bb;
        }
        const float4* w2v0 = (const float4*)(w2 + (size_t)(0 * 128 + d) * CH);
        const float4* w2v1 = (const float4*)(w2 + (size_t)(1 * 128 + d) * CH);
        const float4* w2v2 = (const float4*)(w2 + (size_t)(2 * 128 + d) * CH);
        #pragma unroll 2
        for (int kc = 0; kc < 32; ++kc) {
            float4 h0 = *(const float4*)&hh[mh + 0][kc * 4];
            float4 h1 = *(const float4*)&hh[mh + 1][kc * 4];
            float4 h2 = *(const float4*)&hh[mh + 2][kc * 4];
            float4 h3 = *(const float4*)&hh[mh + 3][kc * 4];
            float4 w0 = w2v0[kc];
            float4 w1r = w2v1[kc];
            float4 w2r = w2v2[kc];
            a[0][0] += w0.x * h0.x + w0.y * h0.y + w0.z * h0.z + w0.w * h0.w;
            a[0][1] += w0.x * h1.x + w0.y * h1.y + w0.z * h1.z + w0.w * h1.w;
            a[0][2] += w0.x * h2.x + w0.y * h2.y + w0.z * h2.z + w0.w * h2.w;
            a[0][3] += w0.x * h3.x + w0.y * h3.y + w0.z * h3.z + w0.w * h3.w;
            a[1][0] += w1r.x * h0.x + w1r.y * h0.y + w1r.z * h0.z + w1r.w * h0.w;
            a[1][1] += w1r.x * h1.x + w1r.y * h1.y + w1r.z * h1.z + w1r.w * h1.w;
            a[1][2] += w1r.x * h2.x + w1r.y * h2.y + w1r.z * h2.z + w1r.w * h2.w;
            a[1][3] += w1r.x * h3.x + w1r.y * h3.y + w1r.z * h3.z + w1r.w * h3.w;
            a[2][0] += w2r.x * h0.x + w2r.y * h0.y + w2r.z * h0.z + w2r.w * h0.w;
            a[2][1] += w2r.x * h1.x + w2r.y * h1.y + w2r.z * h1.z + w2r.w * h1.w;
            a[2][2] += w2r.x * h2.x + w2r.y * h2.y + w2r.z * h2.z + w2r.w * h2.w;
            a[2][3] += w2r.x * h3.x + w2r.y * h3.y + w2r.z * h3.z + w2r.w * h3.w;
        }
        #pragma unroll
        for (int mm = 0; mm < 4; ++mm) {
            float* p = phi + (size_t)(n0 + mh + mm) * 384;
            p[0 * 128 + d] = a[0][mm];
            p[1 * 128 + d] = a[1][mm];
            p[2 * 128 + d] = a[2][mm];
        }
    }
}

// ---------------------------------------------------------------------------
// Gather kernel: one wave (64 lanes) per node. Lane l handles channels
// {2l, 2l+1}. Walks the node's CSR edge list, accumulates in registers,
// writes each output element exactly once (fused with s/v passthrough).
// ---------------------------------------------------------------------------
__global__ __launch_bounds__(256) void gather_kernel(const float* __restrict__ s,
                                                     const float* __restrict__ v,
                                                     const float* __restrict__ phi,
                                                     const float* __restrict__ rbf,
                                                     const float* __restrict__ ev,
                                                     const int* __restrict__ offsets,
                                                     const int* __restrict__ counts,
                                                     const int2* __restrict__ bucket,
                                                     float* __restrict__ out_s,
                                                     float* __restrict__ out_v) {
    const int t = threadIdx.x;
    const int n = blockIdx.x * 4 + (t >> 6);     // 2500 blocks * 4 waves = NN
    const int l = t & 63;

    float2 acc_s = make_float2(0.f, 0.f);
    float2 av0 = make_float2(0.f, 0.f);
    float2 av1 = make_float2(0.f, 0.f);
    float2 av2 = make_float2(0.f, 0.f);

    const int beg = offsets[n];
    const int end = beg + counts[n];

    for (int k = beg; k < end; ++k) {
        const int2 ej = bucket[k];
        const int e = ej.x, j = ej.y;

        const float2* pj = (const float2*)(phi + (size_t)j * 384);
        const float2* rb = (const float2*)(rbf + (size_t)e * 384);

        float2 ps  = pj[l],       rs  = rb[l];
        float2 pvv = pj[64 + l],  rvv = rb[64 + l];
        float2 pvs = pj[128 + l], rvs = rb[128 + l];

        const float2 ms  = make_float2(ps.x * rs.x,   ps.y * rs.y);
        const float2 mvv = make_float2(pvv.x * rvv.x, pvv.y * rvv.y);
        const float2 mvs = make_float2(pvs.x * rvs.x, pvs.y * rvs.y);

        acc_s.x += ms.x; acc_s.y += ms.y;

        const float e0 = ev[(size_t)e * 3 + 0];
        const float e1 = ev[(size_t)e * 3 + 1];
        const float e2 = ev[(size_t)e * 3 + 2];

        const float2* vj = (const float2*)(v + (size_t)j * 384);
        float2 v0 = vj[l], v1 = vj[64 + l], v2 = vj[128 + l];

        av0.x += v0.x * mvv.x + e0 * mvs.x;  av0.y += v0.y * mvv.y + e0 * mvs.y;
        av1.x += v1.x * mvv.x + e1 * mvs.x;  av1.y += v1.y * mvv.y + e1 * mvs.y;
        av2.x += v2.x * mvv.x + e2 * mvs.x;  av2.y += v2.y * mvv.y + e2 * mvs.y;
    }

    // Epilogue: out = input + SCALE * acc (each element written exactly once)
    {
        float2 sv = ((const float2*)(s + (size_t)n * CH))[l];
        float2 o = make_float2(sv.x + SCALE_F * acc_s.x, sv.y + SCALE_F * acc_s.y);
        ((float2*)(out_s + (size_t)n * CH))[l] = o;

        const float2* vn = (const float2*)(v + (size_t)n * 384);
        float2 w0 = vn[l], w1 = vn[64 + l], w2 = vn[128 + l];
        float2 o0 = make_float2(w0.x + SCALE_F * av0.x, w0.y + SCALE_F * av0.y);
        float2 o1 = make_float2(w1.x + SCALE_F * av1.x, w1.y + SCALE_F * av1.y);
        float2 o2 = make_float2(w2.x + SCALE_F * av2.x, w2.y + SCALE_F * av2.y);
        float2* ov = (float2*)(out_v + (size_t)n * 384);
        ov[l] = o0; ov[64 + l] = o1; ov[128 + l] = o2;
    }
}

// ---------------------------------------------------------------------------
extern "C" void kernel_launch(void* const* d_in, const int* in_sizes, int n_in,
                              void* d_out, int out_size, void* d_ws, size_t ws_size,
                              hipStream_t stream) {
    const float* s    = (const float*)d_in[0];
    const float* v    = (const float*)d_in[1];
    const int*   ei   = (const int*)d_in[2];
    const float* rbf  = (const float*)d_in[3];
    const float* ev   = (const float*)d_in[4];
    const float* w1   = (const float*)d_in[5];
    const float* b1   = (const float*)d_in[6];
    const float* w2   = (const float*)d_in[7];
    const float* b2   = (const float*)d_in[8];
    const float* rmsw = (const float*)d_in[9];

    float* out   = (float*)d_out;
    float* out_s = out;                       // [NN,1,CH]
    float* out_v = out + (size_t)NN * CH;     // [NN,3,CH]

    // Workspace layout
    char* ws = (char*)d_ws;
    float* phi   = (float*)ws;                                   ws += (size_t)NN * 384 * sizeof(float);  // 15.36 MB
    int* i64flag = (int*)ws;                                     ws += 64;
    int* counts  = (int*)ws;                                     ws += (size_t)NN * sizeof(int);
    int* offsets = (int*)ws;                                     ws += (size_t)NN * sizeof(int);
    int* cursor  = (int*)ws;                                     ws += (size_t)NN * sizeof(int);
    int2* bucket = (int2*)ws;                                    // NE * 8 B = 1.28 MB

    detect_i64_kernel<<<1, 64, 0, stream>>>(ei, i64flag);
    zero_counts_kernel<<<(NN + 255) / 256, 256, 0, stream>>>(counts);
    count_kernel<<<(NE + 255) / 256, 256, 0, stream>>>(ei, i64flag, counts);
    scan_kernel<<<1, 1024, 0, stream>>>(counts, offsets, cursor);
    bucket_kernel<<<(NE + 255) / 256, 256, 0, stream>>>(ei, i64flag, cursor, bucket);
    phi_kernel<<<NN / 8, 256, 0, stream>>>(s, w1, b1, w2, b2, rmsw, phi);
    gather_kernel<<<NN / 4, 256, 0, stream>>>(s, v, phi, rbf, ev, offsets, counts, bucket,
                                              out_s, out_v);
}

// Round 3
// 504.787 us; speedup vs baseline: 2.8525x; 1.0397x over previous
//
#include <hip/hip_runtime.h>
#include <math.h>

#define NN 10000
#define NE 160000
#define CH 128
#define SCALE_F 0.0625f
#define EPS_F 1.1920929e-07f

// bf16 helpers (RNE rounding)
__device__ __forceinline__ unsigned short f2bf(float x) {
    unsigned int u = __float_as_uint(x);
    u += 0x7FFFu + ((u >> 16) & 1u);
    return (unsigned short)(u >> 16);
}
__device__ __forceinline__ unsigned int pack2bf(float a, float b) {
    return (unsigned int)f2bf(a) | ((unsigned int)f2bf(b) << 16);
}
__device__ __forceinline__ float bf_lo(unsigned int u) { return __uint_as_float(u << 16); }
__device__ __forceinline__ float bf_hi(unsigned int u) { return __uint_as_float(u & 0xFFFF0000u); }

// ---------------------------------------------------------------------------
// Kernel: detect int64-vs-int32 edge_index layout (block 0) + zero counts.
// ---------------------------------------------------------------------------
__global__ __launch_bounds__(256) void detect_zero_kernel(const int* __restrict__ ei,
                                                          int* __restrict__ flag,
                                                          int* __restrict__ counts) {
    int t = blockIdx.x * 256 + threadIdx.x;
    if (t < NN) counts[t] = 0;
    if (blockIdx.x == 0 && threadIdx.x < 64) {
        int val = ei[2 * threadIdx.x + 1];   // high words if int64; random indices if int32
        unsigned long long b = __ballot(val != 0);
        if (threadIdx.x == 0) *flag = (b == 0ULL) ? 1 : 0;
    }
}

__global__ __launch_bounds__(256) void count_kernel(const int* __restrict__ ei,
                                                    const int* __restrict__ flag,
                                                    int* __restrict__ counts) {
    int e = blockIdx.x * 256 + threadIdx.x;
    if (e >= NE) return;
    int i = (*flag) ? ei[2 * (size_t)e] : ei[e];
    atomicAdd(&counts[i], 1);
}

// Single-block exclusive scan over NN counts -> offsets (and cursor copy).
__global__ __launch_bounds__(1024) void scan_kernel(const int* __restrict__ counts,
                                                    int* __restrict__ offsets,
                                                    int* __restrict__ cursor) {
    __shared__ int sm[1024];
    const int t = threadIdx.x;
    const int base = t * 10;                 // 1024*10 = 10240 >= NN
    int vals[10];
    int lsum = 0;
    #pragma unroll
    for (int k = 0; k < 10; ++k) {
        int idx = base + k;
        int v = (idx < NN) ? counts[idx] : 0;
        vals[k] = v;
        lsum += v;
    }
    sm[t] = lsum;
    __syncthreads();
    #pragma unroll
    for (int off = 1; off < 1024; off <<= 1) {
        int add = (t >= off) ? sm[t - off] : 0;
        __syncthreads();
        sm[t] += add;
        __syncthreads();
    }
    int run = sm[t] - lsum;
    #pragma unroll
    for (int k = 0; k < 10; ++k) {
        int idx = base + k;
        if (idx < NN) { offsets[idx] = run; cursor[idx] = run; }
        run += vals[k];
    }
}

__global__ __launch_bounds__(256) void bucket_kernel(const int* __restrict__ ei,
                                                     const int* __restrict__ flag,
                                                     int* __restrict__ cursor,
                                                     int2* __restrict__ bucket) {
    int e = blockIdx.x * 256 + threadIdx.x;
    if (e >= NE) return;
    int i, j;
    if (*flag) {
        i = ei[2 * (size_t)e];
        j = ei[2 * ((size_t)NE + e)];
    } else {
        i = ei[e];
        j = ei[NE + e];
    }
    int pos = atomicAdd(&cursor[i], 1);
    bucket[pos] = make_int2(e, j);
}

// ---------------------------------------------------------------------------
// phi kernel: rec[n] = bf16 [phi_s(128) | phi_vv(128) | phi_vs(128) | v(384)]
// where phi = b2 + w2 @ silu(b1 + w1 @ rmsnorm(s)).  8 nodes/block.
// rec layout in uints (pairs of channels): 384 uints per node.
// ---------------------------------------------------------------------------
__global__ __launch_bounds__(256) void phi_kernel(const float* __restrict__ s,
                                                  const float* __restrict__ v,
                                                  const float* __restrict__ w1,
                                                  const float* __restrict__ b1,
                                                  const float* __restrict__ w2,
                                                  const float* __restrict__ b2,
                                                  const float* __restrict__ rms_w,
                                                  unsigned int* __restrict__ rec) {
    __shared__ float sn[8][132];
    __shared__ float hh[8][132];

    const int t = threadIdx.x;
    const int n0 = blockIdx.x * 8;

    // --- Pack v into rec (independent of the MLP pipeline) ---
    {
        const int m = t >> 5;            // node 0..7
        const int l = t & 31;            // 32 lanes per node
        const int n = n0 + m;
        const float2* vsrc = (const float2*)(v + (size_t)n * 384);
        unsigned int* vdst = rec + (size_t)n * 384 + 192;
        #pragma unroll
        for (int k = 0; k < 6; ++k) {    // 192 pairs, 32 lanes -> 6 iters
            float2 a = vsrc[k * 32 + l];
            vdst[k * 32 + l] = pack2bf(a.x, a.y);
        }
    }

    // --- RMSNorm: thread t handles node m = t>>5, 4 channels at l*4 ---
    {
        const int m = t >> 5;
        const int l = t & 31;
        const int n = n0 + m;
        float4 sv = ((const float4*)(s + (size_t)n * CH))[l];
        float ss = sv.x * sv.x + sv.y * sv.y + sv.z * sv.z + sv.w * sv.w;
        #pragma unroll
        for (int off = 16; off > 0; off >>= 1) ss += __shfl_xor(ss, off, 32);
        const float sc = rsqrtf(ss * (1.0f / CH) + EPS_F);
        float4 rw = ((const float4*)rms_w)[l];
        float4* dst = (float4*)&sn[m][l * 4];
        float4 o;
        o.x = sv.x * sc * rw.x;
        o.y = sv.y * sc * rw.y;
        o.z = sv.z * sc * rw.z;
        o.w = sv.w * sc * rw.w;
        *dst = o;
    }
    __syncthreads();

    const int d  = t & 127;          // output channel
    const int mh = (t >> 7) * 4;     // node sub-group: 0 or 4

    // --- Phase 1: h = silu(s_norm @ w1^T + b1) ---
    {
        float acc0, acc1, acc2, acc3;
        const float bb = b1[d];
        acc0 = acc1 = acc2 = acc3 = bb;
        const float4* w1v = (const float4*)(w1 + (size_t)d * CH);
        #pragma unroll 4
        for (int kc = 0; kc < 32; ++kc) {
            float4 w = w1v[kc];
            float4 s0 = *(const float4*)&sn[mh + 0][kc * 4];
            float4 s1 = *(const float4*)&sn[mh + 1][kc * 4];
            float4 s2 = *(const float4*)&sn[mh + 2][kc * 4];
            float4 s3 = *(const float4*)&sn[mh + 3][kc * 4];
            acc0 += w.x * s0.x + w.y * s0.y + w.z * s0.z + w.w * s0.w;
            acc1 += w.x * s1.x + w.y * s1.y + w.z * s1.z + w.w * s1.w;
            acc2 += w.x * s2.x + w.y * s2.y + w.z * s2.z + w.w * s2.w;
            acc3 += w.x * s3.x + w.y * s3.y + w.z * s3.z + w.w * s3.w;
        }
        hh[mh + 0][d] = acc0 / (1.0f + __expf(-acc0));
        hh[mh + 1][d] = acc1 / (1.0f + __expf(-acc1));
        hh[mh + 2][d] = acc2 / (1.0f + __expf(-acc2));
        hh[mh + 3][d] = acc3 / (1.0f + __expf(-acc3));
    }
    __syncthreads();

    // --- Phase 2: phi = h @ w2^T + b2, stored as bf16 into rec ---
    {
        float a[3][4];
        #pragma unroll
        for (int q = 0; q < 3; ++q) {
            float bb = b2[q * 128 + d];
            a[q][0] = a[q][1] = a[q][2] = a[q][3] = bb;
        }
        const float4* w2v0 = (const float4*)(w2 + (size_t)(0 * 128 + d) * CH);
        const float4* w2v1 = (const float4*)(w2 + (size_t)(1 * 128 + d) * CH);
        const float4* w2v2 = (const float4*)(w2 + (size_t)(2 * 128 + d) * CH);
        #pragma unroll 2
        for (int kc = 0; kc < 32; ++kc) {
            float4 h0 = *(const float4*)&hh[mh + 0][kc * 4];
            float4 h1 = *(const float4*)&hh[mh + 1][kc * 4];
            float4 h2 = *(const float4*)&hh[mh + 2][kc * 4];
            float4 h3 = *(const float4*)&hh[mh + 3][kc * 4];
            float4 w0 = w2v0[kc];
            float4 w1r = w2v1[kc];
            float4 w2r = w2v2[kc];
            a[0][0] += w0.x * h0.x + w0.y * h0.y + w0.z * h0.z + w0.w * h0.w;
            a[0][1] += w0.x * h1.x + w0.y * h1.y + w0.z * h1.z + w0.w * h1.w;
            a[0][2] += w0.x * h2.x + w0.y * h2.y + w0.z * h2.z + w0.w * h2.w;
            a[0][3] += w0.x * h3.x + w0.y * h3.y + w0.z * h3.z + w0.w * h3.w;
            a[1][0] += w1r.x * h0.x + w1r.y * h0.y + w1r.z * h0.z + w1r.w * h0.w;
            a[1][1] += w1r.x * h1.x + w1r.y * h1.y + w1r.z * h1.z + w1r.w * h1.w;
            a[1][2] += w1r.x * h2.x + w1r.y * h2.y + w1r.z * h2.z + w1r.w * h2.w;
            a[1][3] += w1r.x * h3.x + w1r.y * h3.y + w1r.z * h3.z + w1r.w * h3.w;
            a[2][0] += w2r.x * h0.x + w2r.y * h0.y + w2r.z * h0.z + w2r.w * h0.w;
            a[2][1] += w2r.x * h1.x + w2r.y * h1.y + w2r.z * h1.z + w2r.w * h1.w;
            a[2][2] += w2r.x * h2.x + w2r.y * h2.y + w2r.z * h2.z + w2r.w * h2.w;
            a[2][3] += w2r.x * h3.x + w2r.y * h3.y + w2r.z * h3.z + w2r.w * h3.w;
        }
        #pragma unroll
        for (int mm = 0; mm < 4; ++mm) {
            unsigned short* p = (unsigned short*)(rec + (size_t)(n0 + mh + mm) * 384);
            p[0 * 128 + d] = f2bf(a[0][mm]);
            p[1 * 128 + d] = f2bf(a[1][mm]);
            p[2 * 128 + d] = f2bf(a[2][mm]);
        }
    }
}

// ---------------------------------------------------------------------------
// Gather kernel: one wave per node; lane l owns channels {2l, 2l+1}.
// Per edge: 6 dword loads from the bf16 record (phi_s|phi_vv|phi_vs|v0|v1|v2)
// + 3 float2 loads from fp32 rbf + ev + bucket.
// ---------------------------------------------------------------------------
__global__ __launch_bounds__(256) void gather_kernel(const float* __restrict__ s,
                                                     const float* __restrict__ v,
                                                     const unsigned int* __restrict__ rec,
                                                     const float* __restrict__ rbf,
                                                     const float* __restrict__ ev,
                                                     const int* __restrict__ offsets,
                                                     const int* __restrict__ counts,
                                                     const int2* __restrict__ bucket,
                                                     float* __restrict__ out_s,
                                                     float* __restrict__ out_v) {
    const int t = threadIdx.x;
    const int n = blockIdx.x * 4 + (t >> 6);     // 2500 blocks * 4 waves = NN
    const int l = t & 63;

    float2 acc_s = make_float2(0.f, 0.f);
    float2 av0 = make_float2(0.f, 0.f);
    float2 av1 = make_float2(0.f, 0.f);
    float2 av2 = make_float2(0.f, 0.f);

    const int beg = offsets[n];
    const int end = beg + counts[n];

    for (int k = beg; k < end; ++k) {
        const int2 ej = bucket[k];
        const int e = ej.x, j = ej.y;

        const unsigned int* rj = rec + (size_t)j * 384;
        const float2* rb = (const float2*)(rbf + (size_t)e * 384);

        unsigned int u_s  = rj[l];
        unsigned int u_vv = rj[64 + l];
        unsigned int u_vs = rj[128 + l];
        unsigned int u_v0 = rj[192 + l];
        unsigned int u_v1 = rj[256 + l];
        unsigned int u_v2 = rj[320 + l];

        float2 rs  = rb[l];
        float2 rvv = rb[64 + l];
        float2 rvs = rb[128 + l];

        const float e0 = ev[(size_t)e * 3 + 0];
        const float e1 = ev[(size_t)e * 3 + 1];
        const float e2 = ev[(size_t)e * 3 + 2];

        // m_s
        acc_s.x += bf_lo(u_s) * rs.x;
        acc_s.y += bf_hi(u_s) * rs.y;

        const float mvv_x = bf_lo(u_vv) * rvv.x;
        const float mvv_y = bf_hi(u_vv) * rvv.y;
        const float mvs_x = bf_lo(u_vs) * rvs.x;
        const float mvs_y = bf_hi(u_vs) * rvs.y;

        av0.x += bf_lo(u_v0) * mvv_x + e0 * mvs_x;
        av0.y += bf_hi(u_v0) * mvv_y + e0 * mvs_y;
        av1.x += bf_lo(u_v1) * mvv_x + e1 * mvs_x;
        av1.y += bf_hi(u_v1) * mvv_y + e1 * mvs_y;
        av2.x += bf_lo(u_v2) * mvv_x + e2 * mvs_x;
        av2.y += bf_hi(u_v2) * mvv_y + e2 * mvs_y;
    }

    // Epilogue: out = fp32 input + SCALE * acc (exact passthrough term)
    {
        float2 sv = ((const float2*)(s + (size_t)n * CH))[l];
        ((float2*)(out_s + (size_t)n * CH))[l] =
            make_float2(sv.x + SCALE_F * acc_s.x, sv.y + SCALE_F * acc_s.y);

        const float2* vn = (const float2*)(v + (size_t)n * 384);
        float2 w0 = vn[l], w1 = vn[64 + l], w2 = vn[128 + l];
        float2* ov = (float2*)(out_v + (size_t)n * 384);
        ov[l]       = make_float2(w0.x + SCALE_F * av0.x, w0.y + SCALE_F * av0.y);
        ov[64 + l]  = make_float2(w1.x + SCALE_F * av1.x, w1.y + SCALE_F * av1.y);
        ov[128 + l] = make_float2(w2.x + SCALE_F * av2.x, w2.y + SCALE_F * av2.y);
    }
}

// ---------------------------------------------------------------------------
extern "C" void kernel_launch(void* const* d_in, const int* in_sizes, int n_in,
                              void* d_out, int out_size, void* d_ws, size_t ws_size,
                              hipStream_t stream) {
    const float* s    = (const float*)d_in[0];
    const float* v    = (const float*)d_in[1];
    const int*   ei   = (const int*)d_in[2];
    const float* rbf  = (const float*)d_in[3];
    const float* ev   = (const float*)d_in[4];
    const float* w1   = (const float*)d_in[5];
    const float* b1   = (const float*)d_in[6];
    const float* w2   = (const float*)d_in[7];
    const float* b2   = (const float*)d_in[8];
    const float* rmsw = (const float*)d_in[9];

    float* out   = (float*)d_out;
    float* out_s = out;                       // [NN,1,CH]
    float* out_v = out + (size_t)NN * CH;     // [NN,3,CH]

    // Workspace layout
    char* ws = (char*)d_ws;
    unsigned int* rec = (unsigned int*)ws;     ws += (size_t)NN * 384 * sizeof(unsigned int); // 15.36 MB
    int* i64flag = (int*)ws;                   ws += 64;
    int* counts  = (int*)ws;                   ws += (size_t)NN * sizeof(int);
    int* offsets = (int*)ws;                   ws += (size_t)NN * sizeof(int);
    int* cursor  = (int*)ws;                   ws += (size_t)NN * sizeof(int);
    int2* bucket = (int2*)ws;                  // NE * 8 B = 1.28 MB

    detect_zero_kernel<<<(NN + 255) / 256, 256, 0, stream>>>(ei, i64flag, counts);
    count_kernel<<<(NE + 255) / 256, 256, 0, stream>>>(ei, i64flag, counts);
    scan_kernel<<<1, 1024, 0, stream>>>(counts, offsets, cursor);
    bucket_kernel<<<(NE + 255) / 256, 256, 0, stream>>>(ei, i64flag, cursor, bucket);
    phi_kernel<<<NN / 8, 256, 0, stream>>>(s, v, w1, b1, w2, b2, rmsw, rec);
    gather_kernel<<<NN / 4, 256, 0, stream>>>(s, v, rec, rbf, ev, offsets, counts, bucket,
                                              out_s, out_v);
}

// Round 4
// 495.859 us; speedup vs baseline: 2.9039x; 1.0180x over previous
//
#include <hip/hip_runtime.h>
#include <hip/hip_fp16.h>
#include <math.h>

#define NN 10000
#define NE 160000
#define CH 128
#define SCALE_F 0.0625f
#define EPS_F 1.1920929e-07f

// bf16 helpers (RNE rounding)
__device__ __forceinline__ unsigned short f2bf(float x) {
    unsigned int u = __float_as_uint(x);
    u += 0x7FFFu + ((u >> 16) & 1u);
    return (unsigned short)(u >> 16);
}
__device__ __forceinline__ unsigned int pack2bf(float a, float b) {
    return (unsigned int)f2bf(a) | ((unsigned int)f2bf(b) << 16);
}
__device__ __forceinline__ float bf_lo(unsigned int u) { return __uint_as_float(u << 16); }
__device__ __forceinline__ float bf_hi(unsigned int u) { return __uint_as_float(u & 0xFFFF0000u); }
__device__ __forceinline__ float4 bfq(uint2 u) {
    return make_float4(bf_lo(u.x), bf_hi(u.x), bf_lo(u.y), bf_hi(u.y));
}

// ---------------------------------------------------------------------------
// Detect int64-vs-int32 edge_index layout (block 0) + zero counts.
// ---------------------------------------------------------------------------
__global__ __launch_bounds__(256) void detect_zero_kernel(const int* __restrict__ ei,
                                                          int* __restrict__ flag,
                                                          int* __restrict__ counts) {
    int t = blockIdx.x * 256 + threadIdx.x;
    if (t < NN) counts[t] = 0;
    if (blockIdx.x == 0 && threadIdx.x < 64) {
        int val = ei[2 * threadIdx.x + 1];   // high words if int64; random indices if int32
        unsigned long long b = __ballot(val != 0);
        if (threadIdx.x == 0) *flag = (b == 0ULL) ? 1 : 0;
    }
}

__global__ __launch_bounds__(256) void count_kernel(const int* __restrict__ ei,
                                                    const int* __restrict__ flag,
                                                    int* __restrict__ counts) {
    int e = blockIdx.x * 256 + threadIdx.x;
    if (e >= NE) return;
    int i = (*flag) ? ei[2 * (size_t)e] : ei[e];
    atomicAdd(&counts[i], 1);
}

// Single-block exclusive scan over NN counts -> offsets (and cursor copy).
__global__ __launch_bounds__(1024) void scan_kernel(const int* __restrict__ counts,
                                                    int* __restrict__ offsets,
                                                    int* __restrict__ cursor) {
    __shared__ int sm[1024];
    const int t = threadIdx.x;
    const int base = t * 10;                 // 1024*10 = 10240 >= NN
    int vals[10];
    int lsum = 0;
    #pragma unroll
    for (int k = 0; k < 10; ++k) {
        int idx = base + k;
        int v = (idx < NN) ? counts[idx] : 0;
        vals[k] = v;
        lsum += v;
    }
    sm[t] = lsum;
    __syncthreads();
    #pragma unroll
    for (int off = 1; off < 1024; off <<= 1) {
        int add = (t >= off) ? sm[t - off] : 0;
        __syncthreads();
        sm[t] += add;
        __syncthreads();
    }
    int run = sm[t] - lsum;
    #pragma unroll
    for (int k = 0; k < 10; ++k) {
        int idx = base + k;
        if (idx < NN) { offsets[idx] = run; cursor[idx] = run; }
        run += vals[k];
    }
}

// Bucket entry: {e, j, half2(ev0,ev1), half(ev2)} packed into int4 (16 B).
__global__ __launch_bounds__(256) void bucket_kernel(const int* __restrict__ ei,
                                                     const int* __restrict__ flag,
                                                     const float* __restrict__ ev,
                                                     int* __restrict__ cursor,
                                                     int4* __restrict__ bucket) {
    int e = blockIdx.x * 256 + threadIdx.x;
    if (e >= NE) return;
    int i, j;
    if (*flag) {
        i = ei[2 * (size_t)e];
        j = ei[2 * ((size_t)NE + e)];
    } else {
        i = ei[e];
        j = ei[NE + e];
    }
    float e0 = ev[(size_t)e * 3 + 0];
    float e1 = ev[(size_t)e * 3 + 1];
    float e2 = ev[(size_t)e * 3 + 2];
    __half2 h01 = __floats2half2_rn(e0, e1);
    __half  h2v = __float2half_rn(e2);
    unsigned int u01 = *reinterpret_cast<unsigned int*>(&h01);
    unsigned int u2  = (unsigned int)(*reinterpret_cast<unsigned short*>(&h2v));
    int pos = atomicAdd(&cursor[i], 1);
    bucket[pos] = make_int4(e, j, (int)u01, (int)u2);
}

// ---------------------------------------------------------------------------
// phi kernel: rec[n] = bf16 [phi_s(128) | phi_vv(128) | phi_vs(128) | v(384)]
// where phi = b2 + w2 @ silu(b1 + w1 @ rmsnorm(s)).  8 nodes/block.
// ---------------------------------------------------------------------------
__global__ __launch_bounds__(256) void phi_kernel(const float* __restrict__ s,
                                                  const float* __restrict__ v,
                                                  const float* __restrict__ w1,
                                                  const float* __restrict__ b1,
                                                  const float* __restrict__ w2,
                                                  const float* __restrict__ b2,
                                                  const float* __restrict__ rms_w,
                                                  unsigned int* __restrict__ rec) {
    __shared__ float sn[8][132];
    __shared__ float hh[8][132];

    const int t = threadIdx.x;
    const int n0 = blockIdx.x * 8;

    // --- Pack v into rec (independent of the MLP pipeline) ---
    {
        const int m = t >> 5;            // node 0..7
        const int l = t & 31;            // 32 lanes per node
        const int n = n0 + m;
        const float2* vsrc = (const float2*)(v + (size_t)n * 384);
        unsigned int* vdst = rec + (size_t)n * 384 + 192;
        #pragma unroll
        for (int k = 0; k < 6; ++k) {    // 192 pairs, 32 lanes -> 6 iters
            float2 a = vsrc[k * 32 + l];
            vdst[k * 32 + l] = pack2bf(a.x, a.y);
        }
    }

    // --- RMSNorm ---
    {
        const int m = t >> 5;
        const int l = t & 31;
        const int n = n0 + m;
        float4 sv = ((const float4*)(s + (size_t)n * CH))[l];
        float ss = sv.x * sv.x + sv.y * sv.y + sv.z * sv.z + sv.w * sv.w;
        #pragma unroll
        for (int off = 16; off > 0; off >>= 1) ss += __shfl_xor(ss, off, 32);
        const float sc = rsqrtf(ss * (1.0f / CH) + EPS_F);
        float4 rw = ((const float4*)rms_w)[l];
        float4* dst = (float4*)&sn[m][l * 4];
        float4 o;
        o.x = sv.x * sc * rw.x;
        o.y = sv.y * sc * rw.y;
        o.z = sv.z * sc * rw.z;
        o.w = sv.w * sc * rw.w;
        *dst = o;
    }
    __syncthreads();

    const int d  = t & 127;
    const int mh = (t >> 7) * 4;

    // --- Phase 1: h = silu(s_norm @ w1^T + b1) ---
    {
        float acc0, acc1, acc2, acc3;
        const float bb = b1[d];
        acc0 = acc1 = acc2 = acc3 = bb;
        const float4* w1v = (const float4*)(w1 + (size_t)d * CH);
        #pragma unroll 4
        for (int kc = 0; kc < 32; ++kc) {
            float4 w = w1v[kc];
            float4 s0 = *(const float4*)&sn[mh + 0][kc * 4];
            float4 s1 = *(const float4*)&sn[mh + 1][kc * 4];
            float4 s2 = *(const float4*)&sn[mh + 2][kc * 4];
            float4 s3 = *(const float4*)&sn[mh + 3][kc * 4];
            acc0 += w.x * s0.x + w.y * s0.y + w.z * s0.z + w.w * s0.w;
            acc1 += w.x * s1.x + w.y * s1.y + w.z * s1.z + w.w * s1.w;
            acc2 += w.x * s2.x + w.y * s2.y + w.z * s2.z + w.w * s2.w;
            acc3 += w.x * s3.x + w.y * s3.y + w.z * s3.z + w.w * s3.w;
        }
        hh[mh + 0][d] = acc0 / (1.0f + __expf(-acc0));
        hh[mh + 1][d] = acc1 / (1.0f + __expf(-acc1));
        hh[mh + 2][d] = acc2 / (1.0f + __expf(-acc2));
        hh[mh + 3][d] = acc3 / (1.0f + __expf(-acc3));
    }
    __syncthreads();

    // --- Phase 2: phi = h @ w2^T + b2, stored as bf16 into rec ---
    {
        float a[3][4];
        #pragma unroll
        for (int q = 0; q < 3; ++q) {
            float bb = b2[q * 128 + d];
            a[q][0] = a[q][1] = a[q][2] = a[q][3] = bb;
        }
        const float4* w2v0 = (const float4*)(w2 + (size_t)(0 * 128 + d) * CH);
        const float4* w2v1 = (const float4*)(w2 + (size_t)(1 * 128 + d) * CH);
        const float4* w2v2 = (const float4*)(w2 + (size_t)(2 * 128 + d) * CH);
        #pragma unroll 2
        for (int kc = 0; kc < 32; ++kc) {
            float4 h0 = *(const float4*)&hh[mh + 0][kc * 4];
            float4 h1 = *(const float4*)&hh[mh + 1][kc * 4];
            float4 h2 = *(const float4*)&hh[mh + 2][kc * 4];
            float4 h3 = *(const float4*)&hh[mh + 3][kc * 4];
            float4 w0 = w2v0[kc];
            float4 w1r = w2v1[kc];
            float4 w2r = w2v2[kc];
            a[0][0] += w0.x * h0.x + w0.y * h0.y + w0.z * h0.z + w0.w * h0.w;
            a[0][1] += w0.x * h1.x + w0.y * h1.y + w0.z * h1.z + w0.w * h1.w;
            a[0][2] += w0.x * h2.x + w0.y * h2.y + w0.z * h2.z + w0.w * h2.w;
            a[0][3] += w0.x * h3.x + w0.y * h3.y + w0.z * h3.z + w0.w * h3.w;
            a[1][0] += w1r.x * h0.x + w1r.y * h0.y + w1r.z * h0.z + w1r.w * h0.w;
            a[1][1] += w1r.x * h1.x + w1r.y * h1.y + w1r.z * h1.z + w1r.w * h1.w;
            a[1][2] += w1r.x * h2.x + w1r.y * h2.y + w1r.z * h2.z + w1r.w * h2.w;
            a[1][3] += w1r.x * h3.x + w1r.y * h3.y + w1r.z * h3.z + w1r.w * h3.w;
            a[2][0] += w2r.x * h0.x + w2r.y * h0.y + w2r.z * h0.z + w2r.w * h0.w;
            a[2][1] += w2r.x * h1.x + w2r.y * h1.y + w2r.z * h1.z + w2r.w * h1.w;
            a[2][2] += w2r.x * h2.x + w2r.y * h2.y + w2r.z * h2.z + w2r.w * h2.w;
            a[2][3] += w2r.x * h3.x + w2r.y * h3.y + w2r.z * h3.z + w2r.w * h3.w;
        }
        #pragma unroll
        for (int mm = 0; mm < 4; ++mm) {
            unsigned short* p = (unsigned short*)(rec + (size_t)(n0 + mh + mm) * 384);
            p[0 * 128 + d] = f2bf(a[0][mm]);
            p[1 * 128 + d] = f2bf(a[1][mm]);
            p[2 * 128 + d] = f2bf(a[2][mm]);
        }
    }
}

// ---------------------------------------------------------------------------
// Gather kernel: one wave per node, TWO edges per iteration (half-wave split).
// Lane l: half = l>>5 picks edge A/B of the pair; q = l&31 owns channels
// 4q..4q+3. Wide loads: dwordx2 (rec bf16) / dwordx4 (rbf fp32) / dwordx4
// (bucket entry incl. fp16 ev). Next bucket entry prefetched one iter ahead.
// Cross-half __shfl_xor(32) combine, then split-row epilogue.
// ---------------------------------------------------------------------------
__global__ __launch_bounds__(256) void gather_kernel(const float* __restrict__ s,
                                                     const float* __restrict__ v,
                                                     const unsigned int* __restrict__ rec,
                                                     const float* __restrict__ rbf,
                                                     const int* __restrict__ offsets,
                                                     const int* __restrict__ counts,
                                                     const int4* __restrict__ bucket,
                                                     float* __restrict__ out_s,
                                                     float* __restrict__ out_v) {
    const int t = threadIdx.x;
    const int n = blockIdx.x * 4 + (t >> 6);     // 2500 blocks * 4 waves = NN
    const int l = t & 63;
    const int half = l >> 5;
    const int q = l & 31;

    float4 acc_s = make_float4(0.f, 0.f, 0.f, 0.f);
    float4 av0 = acc_s, av1 = acc_s, av2 = acc_s;

    const int beg = offsets[n];
    const int deg = counts[n];
    const int npair = deg >> 1;
    const int4* bk = bucket + beg;

    int4 ent = make_int4(0, 0, 0, 0);
    if (npair > 0) ent = bk[half];

    for (int p = 0; p < npair; ++p) {
        int4 entn = ent;
        if (p + 1 < npair) entn = bk[2 * (p + 1) + half];   // prefetch next pair

        const unsigned int* rj = rec + (size_t)ent.y * 384;
        const float*        rb = rbf + (size_t)ent.x * 384;

        uint2 uS  = ((const uint2*)(rj +   0))[q];
        uint2 uVV = ((const uint2*)(rj +  64))[q];
        uint2 uVS = ((const uint2*)(rj + 128))[q];
        uint2 uV0 = ((const uint2*)(rj + 192))[q];
        uint2 uV1 = ((const uint2*)(rj + 256))[q];
        uint2 uV2 = ((const uint2*)(rj + 320))[q];
        float4 rS  = ((const float4*)(rb +   0))[q];
        float4 rVV = ((const float4*)(rb + 128))[q];
        float4 rVS = ((const float4*)(rb + 256))[q];

        __half2 h01 = *reinterpret_cast<const __half2*>(&ent.z);
        float2 ev01 = __half22float2(h01);
        unsigned short h2u = (unsigned short)(ent.w & 0xFFFF);
        float ev2 = __half2float(*reinterpret_cast<const __half*>(&h2u));

        float4 ps = bfq(uS);
        acc_s.x = fmaf(ps.x, rS.x, acc_s.x);
        acc_s.y = fmaf(ps.y, rS.y, acc_s.y);
        acc_s.z = fmaf(ps.z, rS.z, acc_s.z);
        acc_s.w = fmaf(ps.w, rS.w, acc_s.w);

        float4 pv = bfq(uVV);
        float4 pw = bfq(uVS);
        float4 mvv = make_float4(pv.x * rVV.x, pv.y * rVV.y, pv.z * rVV.z, pv.w * rVV.w);
        float4 mvs = make_float4(pw.x * rVS.x, pw.y * rVS.y, pw.z * rVS.z, pw.w * rVS.w);

        float4 v0 = bfq(uV0), v1 = bfq(uV1), v2 = bfq(uV2);
        av0.x = fmaf(v0.x, mvv.x, fmaf(ev01.x, mvs.x, av0.x));
        av0.y = fmaf(v0.y, mvv.y, fmaf(ev01.x, mvs.y, av0.y));
        av0.z = fmaf(v0.z, mvv.z, fmaf(ev01.x, mvs.z, av0.z));
        av0.w = fmaf(v0.w, mvv.w, fmaf(ev01.x, mvs.w, av0.w));
        av1.x = fmaf(v1.x, mvv.x, fmaf(ev01.y, mvs.x, av1.x));
        av1.y = fmaf(v1.y, mvv.y, fmaf(ev01.y, mvs.y, av1.y));
        av1.z = fmaf(v1.z, mvv.z, fmaf(ev01.y, mvs.z, av1.z));
        av1.w = fmaf(v1.w, mvv.w, fmaf(ev01.y, mvs.w, av1.w));
        av2.x = fmaf(v2.x, mvv.x, fmaf(ev2, mvs.x, av2.x));
        av2.y = fmaf(v2.y, mvv.y, fmaf(ev2, mvs.y, av2.y));
        av2.z = fmaf(v2.z, mvv.z, fmaf(ev2, mvs.z, av2.z));
        av2.w = fmaf(v2.w, mvv.w, fmaf(ev2, mvs.w, av2.w));

        ent = entn;
    }

    // Tail edge (odd degree): lanes of half 0 only.
    if ((deg & 1) && half == 0) {
        int4 te = bk[deg - 1];
        const unsigned int* rj = rec + (size_t)te.y * 384;
        const float*        rb = rbf + (size_t)te.x * 384;

        uint2 uS  = ((const uint2*)(rj +   0))[q];
        uint2 uVV = ((const uint2*)(rj +  64))[q];
        uint2 uVS = ((const uint2*)(rj + 128))[q];
        uint2 uV0 = ((const uint2*)(rj + 192))[q];
        uint2 uV1 = ((const uint2*)(rj + 256))[q];
        uint2 uV2 = ((const uint2*)(rj + 320))[q];
        float4 rS  = ((const float4*)(rb +   0))[q];
        float4 rVV = ((const float4*)(rb + 128))[q];
        float4 rVS = ((const float4*)(rb + 256))[q];

        __half2 h01 = *reinterpret_cast<const __half2*>(&te.z);
        float2 ev01 = __half22float2(h01);
        unsigned short h2u = (unsigned short)(te.w & 0xFFFF);
        float ev2 = __half2float(*reinterpret_cast<const __half*>(&h2u));

        float4 ps = bfq(uS);
        acc_s.x = fmaf(ps.x, rS.x, acc_s.x);
        acc_s.y = fmaf(ps.y, rS.y, acc_s.y);
        acc_s.z = fmaf(ps.z, rS.z, acc_s.z);
        acc_s.w = fmaf(ps.w, rS.w, acc_s.w);

        float4 pv = bfq(uVV);
        float4 pw = bfq(uVS);
        float4 mvv = make_float4(pv.x * rVV.x, pv.y * rVV.y, pv.z * rVV.z, pv.w * rVV.w);
        float4 mvs = make_float4(pw.x * rVS.x, pw.y * rVS.y, pw.z * rVS.z, pw.w * rVS.w);

        float4 v0 = bfq(uV0), v1 = bfq(uV1), v2 = bfq(uV2);
        av0.x = fmaf(v0.x, mvv.x, fmaf(ev01.x, mvs.x, av0.x));
        av0.y = fmaf(v0.y, mvv.y, fmaf(ev01.x, mvs.y, av0.y));
        av0.z = fmaf(v0.z, mvv.z, fmaf(ev01.x, mvs.z, av0.z));
        av0.w = fmaf(v0.w, mvv.w, fmaf(ev01.x, mvs.w, av0.w));
        av1.x = fmaf(v1.x, mvv.x, fmaf(ev01.y, mvs.x, av1.x));
        av1.y = fmaf(v1.y, mvv.y, fmaf(ev01.y, mvs.y, av1.y));
        av1.z = fmaf(v1.z, mvv.z, fmaf(ev01.y, mvs.z, av1.z));
        av1.w = fmaf(v1.w, mvv.w, fmaf(ev01.y, mvs.w, av1.w));
        av2.x = fmaf(v2.x, mvv.x, fmaf(ev2, mvs.x, av2.x));
        av2.y = fmaf(v2.y, mvv.y, fmaf(ev2, mvs.y, av2.y));
        av2.z = fmaf(v2.z, mvv.z, fmaf(ev2, mvs.z, av2.z));
        av2.w = fmaf(v2.w, mvv.w, fmaf(ev2, mvs.w, av2.w));
    }

    // Cross-half reduction: lanes q and q+32 hold the same channels.
    acc_s.x += __shfl_xor(acc_s.x, 32);
    acc_s.y += __shfl_xor(acc_s.y, 32);
    acc_s.z += __shfl_xor(acc_s.z, 32);
    acc_s.w += __shfl_xor(acc_s.w, 32);
    av0.x += __shfl_xor(av0.x, 32);
    av0.y += __shfl_xor(av0.y, 32);
    av0.z += __shfl_xor(av0.z, 32);
    av0.w += __shfl_xor(av0.w, 32);
    av1.x += __shfl_xor(av1.x, 32);
    av1.y += __shfl_xor(av1.y, 32);
    av1.z += __shfl_xor(av1.z, 32);
    av1.w += __shfl_xor(av1.w, 32);
    av2.x += __shfl_xor(av2.x, 32);
    av2.y += __shfl_xor(av2.y, 32);
    av2.z += __shfl_xor(av2.z, 32);
    av2.w += __shfl_xor(av2.w, 32);

    // Epilogue: out = fp32 input + SCALE * acc. Rows split across halves.
    const size_t nb = (size_t)n;
    if (half == 0) {
        float4 sv = ((const float4*)(s + nb * CH))[q];
        ((float4*)(out_s + nb * CH))[q] =
            make_float4(sv.x + SCALE_F * acc_s.x, sv.y + SCALE_F * acc_s.y,
                        sv.z + SCALE_F * acc_s.z, sv.w + SCALE_F * acc_s.w);
        float4 w0 = ((const float4*)(v + nb * 384))[q];
        ((float4*)(out_v + nb * 384))[q] =
            make_float4(w0.x + SCALE_F * av0.x, w0.y + SCALE_F * av0.y,
                        w0.z + SCALE_F * av0.z, w0.w + SCALE_F * av0.w);
    } else {
        float4 w1 = ((const float4*)(v + nb * 384 + 128))[q];
        ((float4*)(out_v + nb * 384 + 128))[q] =
            make_float4(w1.x + SCALE_F * av1.x, w1.y + SCALE_F * av1.y,
                        w1.z + SCALE_F * av1.z, w1.w + SCALE_F * av1.w);
        float4 w2 = ((const float4*)(v + nb * 384 + 256))[q];
        ((float4*)(out_v + nb * 384 + 256))[q] =
            make_float4(w2.x + SCALE_F * av2.x, w2.y + SCALE_F * av2.y,
                        w2.z + SCALE_F * av2.z, w2.w + SCALE_F * av2.w);
    }
}

// ---------------------------------------------------------------------------
extern "C" void kernel_launch(void* const* d_in, const int* in_sizes, int n_in,
                              void* d_out, int out_size, void* d_ws, size_t ws_size,
                              hipStream_t stream) {
    const float* s    = (const float*)d_in[0];
    const float* v    = (const float*)d_in[1];
    const int*   ei   = (const int*)d_in[2];
    const float* rbf  = (const float*)d_in[3];
    const float* ev   = (const float*)d_in[4];
    const float* w1   = (const float*)d_in[5];
    const float* b1   = (const float*)d_in[6];
    const float* w2   = (const float*)d_in[7];
    const float* b2   = (const float*)d_in[8];
    const float* rmsw = (const float*)d_in[9];

    float* out   = (float*)d_out;
    float* out_s = out;                       // [NN,1,CH]
    float* out_v = out + (size_t)NN * CH;     // [NN,3,CH]

    // Workspace layout (all 16B-aligned)
    char* ws = (char*)d_ws;
    unsigned int* rec = (unsigned int*)ws;     ws += (size_t)NN * 384 * sizeof(unsigned int); // 15.36 MB
    int* i64flag = (int*)ws;                   ws += 64;
    int* counts  = (int*)ws;                   ws += (size_t)NN * sizeof(int);
    int* offsets = (int*)ws;                   ws += (size_t)NN * sizeof(int);
    int* cursor  = (int*)ws;                   ws += (size_t)NN * sizeof(int);
    int4* bucket = (int4*)ws;                  // NE * 16 B = 2.56 MB

    detect_zero_kernel<<<(NN + 255) / 256, 256, 0, stream>>>(ei, i64flag, counts);
    count_kernel<<<(NE + 255) / 256, 256, 0, stream>>>(ei, i64flag, counts);
    scan_kernel<<<1, 1024, 0, stream>>>(counts, offsets, cursor);
    bucket_kernel<<<(NE + 255) / 256, 256, 0, stream>>>(ei, i64flag, ev, cursor, bucket);
    phi_kernel<<<NN / 8, 256, 0, stream>>>(s, v, w1, b1, w2, b2, rmsw, rec);
    gather_kernel<<<NN / 4, 256, 0, stream>>>(s, v, rec, rbf, offsets, counts, bucket,
                                              out_s, out_v);
}

// Round 5
// 463.199 us; speedup vs baseline: 3.1086x; 1.0705x over previous
//
#include <hip/hip_runtime.h>
#include <hip/hip_fp16.h>
#include <math.h>

#define NN 10000
#define NE 160000
#define CH 128
#define SCALE_F 0.0625f
#define EPS_F 1.1920929e-07f

// bf16 helpers (RNE rounding)
__device__ __forceinline__ unsigned short f2bf(float x) {
    unsigned int u = __float_as_uint(x);
    u += 0x7FFFu + ((u >> 16) & 1u);
    return (unsigned short)(u >> 16);
}
__device__ __forceinline__ unsigned int pack2bf(float a, float b) {
    return (unsigned int)f2bf(a) | ((unsigned int)f2bf(b) << 16);
}
__device__ __forceinline__ float bf_lo(unsigned int u) { return __uint_as_float(u << 16); }
__device__ __forceinline__ float bf_hi(unsigned int u) { return __uint_as_float(u & 0xFFFF0000u); }
__device__ __forceinline__ float4 bfq(uint2 u) {
    return make_float4(bf_lo(u.x), bf_hi(u.x), bf_lo(u.y), bf_hi(u.y));
}

// ---------------------------------------------------------------------------
// Detect int64-vs-int32 edge_index layout (block 0) + zero counts.
// ---------------------------------------------------------------------------
__global__ __launch_bounds__(256) void detect_zero_kernel(const int* __restrict__ ei,
                                                          int* __restrict__ flag,
                                                          int* __restrict__ counts) {
    int t = blockIdx.x * 256 + threadIdx.x;
    if (t < NN) counts[t] = 0;
    if (blockIdx.x == 0 && threadIdx.x < 64) {
        int val = ei[2 * threadIdx.x + 1];   // high words if int64; random indices if int32
        unsigned long long b = __ballot(val != 0);
        if (threadIdx.x == 0) *flag = (b == 0ULL) ? 1 : 0;
    }
}

// ---------------------------------------------------------------------------
// Weight transpose: w1t[c][d]=w1[d][c] (128x128), w2t[c][d]=w2[d][c] (128x384).
// Writes coalesced; strided reads are absorbed by L2 (total src 256 KB).
// ---------------------------------------------------------------------------
__global__ __launch_bounds__(256) void transpose_w_kernel(const float* __restrict__ w1,
                                                          const float* __restrict__ w2,
                                                          float* __restrict__ w1t,
                                                          float* __restrict__ w2t) {
    int idx = blockIdx.x * 256 + threadIdx.x;   // 0 .. 65535
    if (idx < 128 * 128) {
        int c = idx >> 7, d = idx & 127;
        w1t[c * 128 + d] = w1[d * 128 + c];
    } else {
        int o = idx - 128 * 128;                // 0 .. 49151
        int c = o / 384, d = o - c * 384;
        w2t[c * 384 + d] = w2[d * 128 + c];
    }
}

__global__ __launch_bounds__(256) void count_kernel(const int* __restrict__ ei,
                                                    const int* __restrict__ flag,
                                                    int* __restrict__ counts) {
    int e = blockIdx.x * 256 + threadIdx.x;
    if (e >= NE) return;
    int i = (*flag) ? ei[2 * (size_t)e] : ei[e];
    atomicAdd(&counts[i], 1);
}

// Single-block exclusive scan over NN counts -> offsets (and cursor copy).
__global__ __launch_bounds__(1024) void scan_kernel(const int* __restrict__ counts,
                                                    int* __restrict__ offsets,
                                                    int* __restrict__ cursor) {
    __shared__ int sm[1024];
    const int t = threadIdx.x;
    const int base = t * 10;                 // 1024*10 = 10240 >= NN
    int vals[10];
    int lsum = 0;
    #pragma unroll
    for (int k = 0; k < 10; ++k) {
        int idx = base + k;
        int v = (idx < NN) ? counts[idx] : 0;
        vals[k] = v;
        lsum += v;
    }
    sm[t] = lsum;
    __syncthreads();
    #pragma unroll
    for (int off = 1; off < 1024; off <<= 1) {
        int add = (t >= off) ? sm[t - off] : 0;
        __syncthreads();
        sm[t] += add;
        __syncthreads();
    }
    int run = sm[t] - lsum;
    #pragma unroll
    for (int k = 0; k < 10; ++k) {
        int idx = base + k;
        if (idx < NN) { offsets[idx] = run; cursor[idx] = run; }
        run += vals[k];
    }
}

// Bucket entry: {e, j, half2(ev0,ev1), half(ev2)} packed into int4 (16 B).
__global__ __launch_bounds__(256) void bucket_kernel(const int* __restrict__ ei,
                                                     const int* __restrict__ flag,
                                                     const float* __restrict__ ev,
                                                     int* __restrict__ cursor,
                                                     int4* __restrict__ bucket) {
    int e = blockIdx.x * 256 + threadIdx.x;
    if (e >= NE) return;
    int i, j;
    if (*flag) {
        i = ei[2 * (size_t)e];
        j = ei[2 * ((size_t)NE + e)];
    } else {
        i = ei[e];
        j = ei[NE + e];
    }
    float e0 = ev[(size_t)e * 3 + 0];
    float e1 = ev[(size_t)e * 3 + 1];
    float e2 = ev[(size_t)e * 3 + 2];
    __half2 h01 = __floats2half2_rn(e0, e1);
    __half  h2v = __float2half_rn(e2);
    unsigned int u01 = *reinterpret_cast<unsigned int*>(&h01);
    unsigned int u2  = (unsigned int)(*reinterpret_cast<unsigned short*>(&h2v));
    int pos = atomicAdd(&cursor[i], 1);
    bucket[pos] = make_int4(e, j, (int)u01, (int)u2);
}

// ---------------------------------------------------------------------------
// phi kernel (transposed-weight, output-stationary):
// 625 blocks x 128 threads (2 waves); each wave owns 8 nodes.
// Lane: half=l>>5 handles c-parity, q=l&31 owns output channels 4q..4q+3.
// Weight loads from w1t/w2t are coalesced; x/h broadcast from LDS.
// rec[n] = bf16 [phi_s(128) | phi_vv(128) | phi_vs(128) | v(384)].
// ---------------------------------------------------------------------------
__global__ __launch_bounds__(128) void phi_kernel(const float* __restrict__ s,
                                                  const float* __restrict__ v,
                                                  const float* __restrict__ w1t,
                                                  const float* __restrict__ b1,
                                                  const float* __restrict__ w2t,
                                                  const float* __restrict__ b2,
                                                  const float* __restrict__ rms_w,
                                                  unsigned int* __restrict__ rec) {
    __shared__ float xw[2][8][128];
    __shared__ float hh[2][8][128];

    const int t = threadIdx.x;      // 0..127
    const int wv = t >> 6;          // wave 0/1
    const int l = t & 63;
    const int half = l >> 5;        // c-parity half
    const int q = l & 31;           // output-channel group
    const int nbase = blockIdx.x * 16 + wv * 8;

    // --- Pack v into rec (independent of the MLP pipeline) ---
    #pragma unroll
    for (int n = 0; n < 8; ++n) {
        const int gn = nbase + n;
        const float2* vsrc = (const float2*)(v + (size_t)gn * 384);
        unsigned int* vdst = rec + (size_t)gn * 384 + 192;
        #pragma unroll
        for (int k = 0; k < 3; ++k) {
            float2 a = vsrc[k * 64 + l];
            vdst[k * 64 + l] = pack2bf(a.x, a.y);
        }
    }

    // --- RMSNorm: each half-wave handles 4 nodes, 32 lanes x float4 ---
    {
        const float4 rw = ((const float4*)rms_w)[q];
        #pragma unroll
        for (int r = 0; r < 4; ++r) {
            const int n = half * 4 + r;
            const int gn = nbase + n;
            float4 sv = ((const float4*)(s + (size_t)gn * CH))[q];
            float ss = sv.x * sv.x + sv.y * sv.y + sv.z * sv.z + sv.w * sv.w;
            #pragma unroll
            for (int off = 16; off > 0; off >>= 1) ss += __shfl_xor(ss, off, 32);
            const float sc = rsqrtf(ss * (1.0f / CH) + EPS_F);
            float4 o;
            o.x = sv.x * sc * rw.x;
            o.y = sv.y * sc * rw.y;
            o.z = sv.z * sc * rw.z;
            o.w = sv.w * sc * rw.w;
            *(float4*)&xw[wv][n][q * 4] = o;
        }
    }
    __syncthreads();

    // --- Phase 1: h = silu(x @ w1t + b1); halves split c, coalesced weights ---
    {
        float4 acc[8];
        const float4 bia = ((const float4*)b1)[q];
        #pragma unroll
        for (int n = 0; n < 8; ++n)
            acc[n] = (half == 0) ? bia : make_float4(0.f, 0.f, 0.f, 0.f);

        #pragma unroll 4
        for (int it = 0; it < 64; ++it) {
            const int c = 2 * it + half;
            const float4 w = *(const float4*)(w1t + (size_t)c * 128 + 4 * q);
            #pragma unroll
            for (int n = 0; n < 8; ++n) {
                const float xv = xw[wv][n][c];
                acc[n].x = fmaf(xv, w.x, acc[n].x);
                acc[n].y = fmaf(xv, w.y, acc[n].y);
                acc[n].z = fmaf(xv, w.z, acc[n].z);
                acc[n].w = fmaf(xv, w.w, acc[n].w);
            }
        }
        #pragma unroll
        for (int n = 0; n < 8; ++n) {
            acc[n].x += __shfl_xor(acc[n].x, 32);
            acc[n].y += __shfl_xor(acc[n].y, 32);
            acc[n].z += __shfl_xor(acc[n].z, 32);
            acc[n].w += __shfl_xor(acc[n].w, 32);
        }
        #pragma unroll
        for (int r = 0; r < 4; ++r) {
            const int n = half * 4 + r;
            float4 a = acc[n];
            a.x = a.x / (1.0f + __expf(-a.x));
            a.y = a.y / (1.0f + __expf(-a.y));
            a.z = a.z / (1.0f + __expf(-a.z));
            a.w = a.w / (1.0f + __expf(-a.w));
            *(float4*)&hh[wv][n][q * 4] = a;
        }
    }
    __syncthreads();

    // --- Phase 2: phi = h @ w2t + b2, three 128-wide segment passes ---
    #pragma unroll 1
    for (int sg = 0; sg < 3; ++sg) {
        float4 acc[8];
        const float4 bia = ((const float4*)(b2 + 128 * sg))[q];
        #pragma unroll
        for (int n = 0; n < 8; ++n)
            acc[n] = (half == 0) ? bia : make_float4(0.f, 0.f, 0.f, 0.f);

        #pragma unroll 4
        for (int it = 0; it < 64; ++it) {
            const int c = 2 * it + half;
            const float4 w = *(const float4*)(w2t + (size_t)c * 384 + 128 * sg + 4 * q);
            #pragma unroll
            for (int n = 0; n < 8; ++n) {
                const float hv = hh[wv][n][c];
                acc[n].x = fmaf(hv, w.x, acc[n].x);
                acc[n].y = fmaf(hv, w.y, acc[n].y);
                acc[n].z = fmaf(hv, w.z, acc[n].z);
                acc[n].w = fmaf(hv, w.w, acc[n].w);
            }
        }
        #pragma unroll
        for (int n = 0; n < 8; ++n) {
            acc[n].x += __shfl_xor(acc[n].x, 32);
            acc[n].y += __shfl_xor(acc[n].y, 32);
            acc[n].z += __shfl_xor(acc[n].z, 32);
            acc[n].w += __shfl_xor(acc[n].w, 32);
        }
        #pragma unroll
        for (int r = 0; r < 4; ++r) {
            const int n = half * 4 + r;
            uint2 pk;
            pk.x = pack2bf(acc[n].x, acc[n].y);
            pk.y = pack2bf(acc[n].z, acc[n].w);
            *(uint2*)(rec + (size_t)(nbase + n) * 384 + 64 * sg + 2 * q) = pk;
        }
    }
}

// ---------------------------------------------------------------------------
// Gather kernel: one wave per node, TWO edges per iteration (half-wave split).
// ---------------------------------------------------------------------------
__global__ __launch_bounds__(256) void gather_kernel(const float* __restrict__ s,
                                                     const float* __restrict__ v,
                                                     const unsigned int* __restrict__ rec,
                                                     const float* __restrict__ rbf,
                                                     const int* __restrict__ offsets,
                                                     const int* __restrict__ counts,
                                                     const int4* __restrict__ bucket,
                                                     float* __restrict__ out_s,
                                                     float* __restrict__ out_v) {
    const int t = threadIdx.x;
    const int n = blockIdx.x * 4 + (t >> 6);     // 2500 blocks * 4 waves = NN
    const int l = t & 63;
    const int half = l >> 5;
    const int q = l & 31;

    float4 acc_s = make_float4(0.f, 0.f, 0.f, 0.f);
    float4 av0 = acc_s, av1 = acc_s, av2 = acc_s;

    const int beg = offsets[n];
    const int deg = counts[n];
    const int npair = deg >> 1;
    const int4* bk = bucket + beg;

    int4 ent = make_int4(0, 0, 0, 0);
    if (npair > 0) ent = bk[half];

    for (int p = 0; p < npair; ++p) {
        int4 entn = ent;
        if (p + 1 < npair) entn = bk[2 * (p + 1) + half];   // prefetch next pair

        const unsigned int* rj = rec + (size_t)ent.y * 384;
        const float*        rb = rbf + (size_t)ent.x * 384;

        uint2 uS  = ((const uint2*)(rj +   0))[q];
        uint2 uVV = ((const uint2*)(rj +  64))[q];
        uint2 uVS = ((const uint2*)(rj + 128))[q];
        uint2 uV0 = ((const uint2*)(rj + 192))[q];
        uint2 uV1 = ((const uint2*)(rj + 256))[q];
        uint2 uV2 = ((const uint2*)(rj + 320))[q];
        float4 rS  = ((const float4*)(rb +   0))[q];
        float4 rVV = ((const float4*)(rb + 128))[q];
        float4 rVS = ((const float4*)(rb + 256))[q];

        __half2 h01 = *reinterpret_cast<const __half2*>(&ent.z);
        float2 ev01 = __half22float2(h01);
        unsigned short h2u = (unsigned short)(ent.w & 0xFFFF);
        float ev2 = __half2float(*reinterpret_cast<const __half*>(&h2u));

        float4 ps = bfq(uS);
        acc_s.x = fmaf(ps.x, rS.x, acc_s.x);
        acc_s.y = fmaf(ps.y, rS.y, acc_s.y);
        acc_s.z = fmaf(ps.z, rS.z, acc_s.z);
        acc_s.w = fmaf(ps.w, rS.w, acc_s.w);

        float4 pv = bfq(uVV);
        float4 pw = bfq(uVS);
        float4 mvv = make_float4(pv.x * rVV.x, pv.y * rVV.y, pv.z * rVV.z, pv.w * rVV.w);
        float4 mvs = make_float4(pw.x * rVS.x, pw.y * rVS.y, pw.z * rVS.z, pw.w * rVS.w);

        float4 v0 = bfq(uV0), v1 = bfq(uV1), v2 = bfq(uV2);
        av0.x = fmaf(v0.x, mvv.x, fmaf(ev01.x, mvs.x, av0.x));
        av0.y = fmaf(v0.y, mvv.y, fmaf(ev01.x, mvs.y, av0.y));
        av0.z = fmaf(v0.z, mvv.z, fmaf(ev01.x, mvs.z, av0.z));
        av0.w = fmaf(v0.w, mvv.w, fmaf(ev01.x, mvs.w, av0.w));
        av1.x = fmaf(v1.x, mvv.x, fmaf(ev01.y, mvs.x, av1.x));
        av1.y = fmaf(v1.y, mvv.y, fmaf(ev01.y, mvs.y, av1.y));
        av1.z = fmaf(v1.z, mvv.z, fmaf(ev01.y, mvs.z, av1.z));
        av1.w = fmaf(v1.w, mvv.w, fmaf(ev01.y, mvs.w, av1.w));
        av2.x = fmaf(v2.x, mvv.x, fmaf(ev2, mvs.x, av2.x));
        av2.y = fmaf(v2.y, mvv.y, fmaf(ev2, mvs.y, av2.y));
        av2.z = fmaf(v2.z, mvv.z, fmaf(ev2, mvs.z, av2.z));
        av2.w = fmaf(v2.w, mvv.w, fmaf(ev2, mvs.w, av2.w));

        ent = entn;
    }

    // Tail edge (odd degree): lanes of half 0 only.
    if ((deg & 1) && half == 0) {
        int4 te = bk[deg - 1];
        const unsigned int* rj = rec + (size_t)te.y * 384;
        const float*        rb = rbf + (size_t)te.x * 384;

        uint2 uS  = ((const uint2*)(rj +   0))[q];
        uint2 uVV = ((const uint2*)(rj +  64))[q];
        uint2 uVS = ((const uint2*)(rj + 128))[q];
        uint2 uV0 = ((const uint2*)(rj + 192))[q];
        uint2 uV1 = ((const uint2*)(rj + 256))[q];
        uint2 uV2 = ((const uint2*)(rj + 320))[q];
        float4 rS  = ((const float4*)(rb +   0))[q];
        float4 rVV = ((const float4*)(rb + 128))[q];
        float4 rVS = ((const float4*)(rb + 256))[q];

        __half2 h01 = *reinterpret_cast<const __half2*>(&te.z);
        float2 ev01 = __half22float2(h01);
        unsigned short h2u = (unsigned short)(te.w & 0xFFFF);
        float ev2 = __half2float(*reinterpret_cast<const __half*>(&h2u));

        float4 ps = bfq(uS);
        acc_s.x = fmaf(ps.x, rS.x, acc_s.x);
        acc_s.y = fmaf(ps.y, rS.y, acc_s.y);
        acc_s.z = fmaf(ps.z, rS.z, acc_s.z);
        acc_s.w = fmaf(ps.w, rS.w, acc_s.w);

        float4 pv = bfq(uVV);
        float4 pw = bfq(uVS);
        float4 mvv = make_float4(pv.x * rVV.x, pv.y * rVV.y, pv.z * rVV.z, pv.w * rVV.w);
        float4 mvs = make_float4(pw.x * rVS.x, pw.y * rVS.y, pw.z * rVS.z, pw.w * rVS.w);

        float4 v0 = bfq(uV0), v1 = bfq(uV1), v2 = bfq(uV2);
        av0.x = fmaf(v0.x, mvv.x, fmaf(ev01.x, mvs.x, av0.x));
        av0.y = fmaf(v0.y, mvv.y, fmaf(ev01.x, mvs.y, av0.y));
        av0.z = fmaf(v0.z, mvv.z, fmaf(ev01.x, mvs.z, av0.z));
        av0.w = fmaf(v0.w, mvv.w, fmaf(ev01.x, mvs.w, av0.w));
        av1.x = fmaf(v1.x, mvv.x, fmaf(ev01.y, mvs.x, av1.x));
        av1.y = fmaf(v1.y, mvv.y, fmaf(ev01.y, mvs.y, av1.y));
        av1.z = fmaf(v1.z, mvv.z, fmaf(ev01.y, mvs.z, av1.z));
        av1.w = fmaf(v1.w, mvv.w, fmaf(ev01.y, mvs.w, av1.w));
        av2.x = fmaf(v2.x, mvv.x, fmaf(ev2, mvs.x, av2.x));
        av2.y = fmaf(v2.y, mvv.y, fmaf(ev2, mvs.y, av2.y));
        av2.z = fmaf(v2.z, mvv.z, fmaf(ev2, mvs.z, av2.z));
        av2.w = fmaf(v2.w, mvv.w, fmaf(ev2, mvs.w, av2.w));
    }

    // Cross-half reduction: lanes q and q+32 hold the same channels.
    acc_s.x += __shfl_xor(acc_s.x, 32);
    acc_s.y += __shfl_xor(acc_s.y, 32);
    acc_s.z += __shfl_xor(acc_s.z, 32);
    acc_s.w += __shfl_xor(acc_s.w, 32);
    av0.x += __shfl_xor(av0.x, 32);
    av0.y += __shfl_xor(av0.y, 32);
    av0.z += __shfl_xor(av0.z, 32);
    av0.w += __shfl_xor(av0.w, 32);
    av1.x += __shfl_xor(av1.x, 32);
    av1.y += __shfl_xor(av1.y, 32);
    av1.z += __shfl_xor(av1.z, 32);
    av1.w += __shfl_xor(av1.w, 32);
    av2.x += __shfl_xor(av2.x, 32);
    av2.y += __shfl_xor(av2.y, 32);
    av2.z += __shfl_xor(av2.z, 32);
    av2.w += __shfl_xor(av2.w, 32);

    // Epilogue: out = fp32 input + SCALE * acc. Rows split across halves.
    const size_t nb = (size_t)n;
    if (half == 0) {
        float4 sv = ((const float4*)(s + nb * CH))[q];
        ((float4*)(out_s + nb * CH))[q] =
            make_float4(sv.x + SCALE_F * acc_s.x, sv.y + SCALE_F * acc_s.y,
                        sv.z + SCALE_F * acc_s.z, sv.w + SCALE_F * acc_s.w);
        float4 w0 = ((const float4*)(v + nb * 384))[q];
        ((float4*)(out_v + nb * 384))[q] =
            make_float4(w0.x + SCALE_F * av0.x, w0.y + SCALE_F * av0.y,
                        w0.z + SCALE_F * av0.z, w0.w + SCALE_F * av0.w);
    } else {
        float4 w1 = ((const float4*)(v + nb * 384 + 128))[q];
        ((float4*)(out_v + nb * 384 + 128))[q] =
            make_float4(w1.x + SCALE_F * av1.x, w1.y + SCALE_F * av1.y,
                        w1.z + SCALE_F * av1.z, w1.w + SCALE_F * av1.w);
        float4 w2 = ((const float4*)(v + nb * 384 + 256))[q];
        ((float4*)(out_v + nb * 384 + 256))[q] =
            make_float4(w2.x + SCALE_F * av2.x, w2.y + SCALE_F * av2.y,
                        w2.z + SCALE_F * av2.z, w2.w + SCALE_F * av2.w);
    }
}

// ---------------------------------------------------------------------------
extern "C" void kernel_launch(void* const* d_in, const int* in_sizes, int n_in,
                              void* d_out, int out_size, void* d_ws, size_t ws_size,
                              hipStream_t stream) {
    const float* s    = (const float*)d_in[0];
    const float* v    = (const float*)d_in[1];
    const int*   ei   = (const int*)d_in[2];
    const float* rbf  = (const float*)d_in[3];
    const float* ev   = (const float*)d_in[4];
    const float* w1   = (const float*)d_in[5];
    const float* b1   = (const float*)d_in[6];
    const float* w2   = (const float*)d_in[7];
    const float* b2   = (const float*)d_in[8];
    const float* rmsw = (const float*)d_in[9];

    float* out   = (float*)d_out;
    float* out_s = out;                       // [NN,1,CH]
    float* out_v = out + (size_t)NN * CH;     // [NN,3,CH]

    // Workspace layout (all 16B-aligned)
    char* ws = (char*)d_ws;
    unsigned int* rec = (unsigned int*)ws;     ws += (size_t)NN * 384 * sizeof(unsigned int); // 15.36 MB
    int* i64flag = (int*)ws;                   ws += 64;
    int* counts  = (int*)ws;                   ws += (size_t)NN * sizeof(int);
    int* offsets = (int*)ws;                   ws += (size_t)NN * sizeof(int);
    int* cursor  = (int*)ws;                   ws += (size_t)NN * sizeof(int) + 48; // re-align 16B
    int4* bucket = (int4*)ws;                  ws += (size_t)NE * sizeof(int4);     // 2.56 MB
    float* w1t   = (float*)ws;                 ws += (size_t)128 * 128 * sizeof(float); // 64 KB
    float* w2t   = (float*)ws;                 // 192 KB

    detect_zero_kernel<<<(NN + 255) / 256, 256, 0, stream>>>(ei, i64flag, counts);
    transpose_w_kernel<<<256, 256, 0, stream>>>(w1, w2, w1t, w2t);
    count_kernel<<<(NE + 255) / 256, 256, 0, stream>>>(ei, i64flag, counts);
    scan_kernel<<<1, 1024, 0, stream>>>(counts, offsets, cursor);
    bucket_kernel<<<(NE + 255) / 256, 256, 0, stream>>>(ei, i64flag, ev, cursor, bucket);
    phi_kernel<<<NN / 16, 128, 0, stream>>>(s, v, w1t, b1, w2t, b2, rmsw, rec);
    gather_kernel<<<NN / 4, 256, 0, stream>>>(s, v, rec, rbf, offsets, counts, bucket,
                                              out_s, out_v);
}